// Round 6
// baseline (297.588 us; speedup 1.0000x reference)
//
#include <hip/hip_runtime.h>
#include <hip/hip_fp16.h>
#include <math.h>

// GAT 2-layer forward, MI355X. FP32 in/out, int32 edge_index.
// R6: agg1 2-edge-parallel half2 gathers + fused gemm2/att2 epilogue
// (out1 never hits global; gemm2 kernel removed); agg2 8-edge-parallel
// float2 gathers; gemm1 xs transposed for ds_read_b128; CHK 2048.

#define LRELU(v) ((v) > 0.f ? (v) : 0.2f * (v))
#define CAP 128          // agg LDS edge cache per node
#define BSH 8            // 256 nodes per bucket
#define BCAP 5120        // staged capacity per bucket
#define CHK 2048         // edges per k_scatter block

// Pass 1: bin edges by dst bucket, stage reordered in LDS, flush dense runs.
__global__ __launch_bounds__(256) void k_scatter(const int* __restrict__ ei, int* __restrict__ cursor,
                                                 int* __restrict__ stage, int E, int NBK) {
    __shared__ int sval[CHK];
    __shared__ int gaddr[CHK];
    __shared__ int sdst[CHK];
    __shared__ int hist[512];
    __shared__ int lbase[512];
    __shared__ int cnt2[512];
    __shared__ int gdelta[512];
    __shared__ int sA[512];
    int tid = threadIdx.x;
    int e0 = blockIdx.x * CHK;
    int nedge = E - e0; if (nedge > CHK) nedge = CHK;

    for (int i = tid; i < 512; i += 256) { hist[i] = 0; cnt2[i] = 0; }
    __syncthreads();
    for (int j = tid; j < nedge; j += 256) {
        int d = ei[E + e0 + j];
        sdst[j] = d;
        atomicAdd(&hist[d >> BSH], 1);
    }
    __syncthreads();
    sA[tid] = hist[tid]; sA[tid + 256] = hist[tid + 256];
    __syncthreads();
    for (int off = 1; off < 512; off <<= 1) {
        int r0 = sA[tid] + ((tid >= off) ? sA[tid - off] : 0);
        int r1 = sA[tid + 256] + ((tid + 256 >= off) ? sA[tid + 256 - off] : 0);
        __syncthreads();
        sA[tid] = r0; sA[tid + 256] = r1;
        __syncthreads();
    }
    for (int i = tid; i < 512; i += 256) lbase[i] = sA[i] - hist[i];
    __syncthreads();
    for (int b = tid; b < NBK; b += 256) {
        int c = hist[b];
        if (c > 0) {
            int rel = atomicAdd(&cursor[b], c);
            gdelta[b] = b * BCAP + rel - lbase[b];
        }
    }
    __syncthreads();
    for (int j = tid; j < nedge; j += 256) {
        int s = ei[e0 + j];
        int d = sdst[j];
        int b = d >> BSH;
        int r = atomicAdd(&cnt2[b], 1);
        int slot = lbase[b] + r;
        sval[slot]  = s | ((d & ((1 << BSH) - 1)) << 17);
        gaddr[slot] = gdelta[b] + slot;
    }
    __syncthreads();
    for (int s = tid; s < nedge; s += 256) stage[gaddr[s]] = sval[s];
}

// exclusive scan of bucket counts -> gbase[NBK+1]; row_start[N] tail
__global__ __launch_bounds__(256) void k_bucket_scan(const int* __restrict__ cursor,
                                                     int* __restrict__ gbase,
                                                     int* __restrict__ row_start,
                                                     int NBK, int E, int N) {
    __shared__ int sA[512];
    __shared__ int cnt[512];
    int tid = threadIdx.x;
    for (int i = tid; i < 512; i += 256)
        cnt[i] = (i < NBK) ? cursor[i] : 0;
    __syncthreads();
    sA[tid] = cnt[tid]; sA[tid + 256] = cnt[tid + 256];
    __syncthreads();
    for (int off = 1; off < 512; off <<= 1) {
        int r0 = sA[tid] + ((tid >= off) ? sA[tid - off] : 0);
        int r1 = sA[tid + 256] + ((tid + 256 >= off) ? sA[tid + 256 - off] : 0);
        __syncthreads();
        sA[tid] = r0; sA[tid + 256] = r1;
        __syncthreads();
    }
    for (int i = tid; i < 512; i += 256)
        if (i < NBK) gbase[i] = sA[i] - cnt[i];
    if (tid == 0) { gbase[NBK] = E; row_start[N] = E + N; }
}

// Pass 2: per-bucket fine CSR build (L2-hot window -> dense writeback)
__global__ __launch_bounds__(256) void k_build(const int* __restrict__ stage,
                                               const int* __restrict__ gbase,
                                               int* __restrict__ row_start,
                                               int* __restrict__ csr, int N) {
    __shared__ int cnt[256];
    __shared__ int lb[256];
    __shared__ int cur[256];
    __shared__ int sA[256];
    int b = blockIdx.x, tid = threadIdx.x;
    int nodes0 = b << BSH;
    int nnodes = N - nodes0; if (nnodes > 256) nnodes = 256;
    int ebase = gbase[b];
    int ecnt = gbase[b + 1] - ebase;
    const int* sbk = stage + b * BCAP;
    cnt[tid] = (tid < nnodes) ? 1 : 0;  // self loop
    __syncthreads();
    for (int e = tid; e < ecnt; e += 256) {
        int l = (sbk[e] >> 17) & 255;
        atomicAdd(&cnt[l], 1);
    }
    __syncthreads();
    int myc = cnt[tid];
    sA[tid] = myc;
    __syncthreads();
    for (int off = 1; off < 256; off <<= 1) {
        int r = sA[tid] + ((tid >= off) ? sA[tid - off] : 0);
        __syncthreads();
        sA[tid] = r;
        __syncthreads();
    }
    int gb = ebase + nodes0;
    lb[tid] = sA[tid] - myc;
    cur[tid] = 1;
    __syncthreads();
    if (tid < nnodes) {
        row_start[nodes0 + tid] = gb + lb[tid];
        csr[gb + lb[tid]] = nodes0 + tid;
    }
    __syncthreads();
    for (int e = tid; e < ecnt; e += 256) {
        int v = sbk[e];
        int l = (v >> 17) & 255;
        int src = v & 0x1FFFF;
        int r = atomicAdd(&cur[l], 1);
        csr[gb + lb[l] + r] = src;
    }
}

// h1[N,64](fp16) = x[N,128] @ W1[128,64]; 64x64 tile, 4x4/thread, fused att dots
__global__ __launch_bounds__(256) void k_gemm1(const float* __restrict__ x,
                                               const float* __restrict__ W1,
                                               const float* __restrict__ att_src,
                                               const float* __restrict__ att_dst,
                                               __half* __restrict__ h1, float* __restrict__ a_src,
                                               float* __restrict__ a_dst, int N) {
    __shared__ float ws[64][64];
    __shared__ float xs[64][68];   // TRANSPOSED: [k][node], pad 4
    int tid = threadIdx.x;
    int tc = tid & 15, tr = tid >> 4;
    int n0 = blockIdx.x * 64;
    float acc[4][4];
    #pragma unroll
    for (int a = 0; a < 4; a++)
        #pragma unroll
        for (int b = 0; b < 4; b++) acc[a][b] = 0.f;

    for (int kb = 0; kb < 2; kb++) {
        __syncthreads();
        #pragma unroll
        for (int r = 0; r < 4; r++) {
            int i = tid + 256 * r;
            int k = i >> 4, c4 = (i & 15) * 4;
            *(float4*)&ws[k][c4] = *(const float4*)&W1[(size_t)(kb * 64 + k) * 64 + c4];
        }
        #pragma unroll
        for (int r = 0; r < 4; r++) {
            int i = tid + 256 * r;
            int node = i >> 4, k4 = (i & 15) * 4;
            int n = n0 + node;
            float4 v = make_float4(0.f, 0.f, 0.f, 0.f);
            if (n < N) v = *(const float4*)&x[(size_t)n * 128 + kb * 64 + k4];
            xs[k4 + 0][node] = v.x; xs[k4 + 1][node] = v.y;
            xs[k4 + 2][node] = v.z; xs[k4 + 3][node] = v.w;
        }
        __syncthreads();
        #pragma unroll 8
        for (int k = 0; k < 64; k++) {
            float w0 = ws[k][tc * 4 + 0], w1 = ws[k][tc * 4 + 1];
            float w2 = ws[k][tc * 4 + 2], w3 = ws[k][tc * 4 + 3];
            float x0 = xs[k][tr * 4 + 0], x1 = xs[k][tr * 4 + 1];
            float x2 = xs[k][tr * 4 + 2], x3 = xs[k][tr * 4 + 3];
            acc[0][0] += x0 * w0; acc[0][1] += x0 * w1; acc[0][2] += x0 * w2; acc[0][3] += x0 * w3;
            acc[1][0] += x1 * w0; acc[1][1] += x1 * w1; acc[1][2] += x1 * w2; acc[1][3] += x1 * w3;
            acc[2][0] += x2 * w0; acc[2][1] += x2 * w1; acc[2][2] += x2 * w2; acc[2][3] += x2 * w3;
            acc[3][0] += x3 * w0; acc[3][1] += x3 * w1; acc[3][2] += x3 * w2; acc[3][3] += x3 * w3;
        }
    }
    int h = tc >> 2;
    #pragma unroll
    for (int ii = 0; ii < 4; ii++) {
        int n = n0 + tr * 4 + ii;
        float asv = 0.f, adv = 0.f;
        #pragma unroll
        for (int i = 0; i < 4; i++) {
            int cm = (tc & 3) * 4 + i;
            asv += acc[ii][i] * att_src[h * 16 + cm];
            adv += acc[ii][i] * att_dst[h * 16 + cm];
        }
        asv += __shfl_xor(asv, 1, 64); asv += __shfl_xor(asv, 2, 64);
        adv += __shfl_xor(adv, 1, 64); adv += __shfl_xor(adv, 2, 64);
        if (n < N) {
            union { __half2 h2[2]; float2 f2; } u;
            u.h2[0] = __floats2half2_rn(acc[ii][0], acc[ii][1]);
            u.h2[1] = __floats2half2_rn(acc[ii][2], acc[ii][3]);
            *(float2*)&h1[(size_t)n * 64 + tc * 4] = u.f2;
            if ((tc & 3) == 0) { a_src[n * 4 + h] = asv; a_dst[n * 4 + h] = adv; }
        }
    }
}

// layer-1 aggregation + ELU + FUSED layer-2 linear (h2 = out1@W2) + att2 dots.
// One wave per node; 2-edge-parallel half2 gathers.
__global__ __launch_bounds__(256) void k_agg1(const int* __restrict__ row_start,
                                              const int* __restrict__ csr_src,
                                              const float* __restrict__ a_src,
                                              const float* __restrict__ a_dst,
                                              const __half* __restrict__ h1,
                                              const float* __restrict__ bias,
                                              const float* __restrict__ W2,
                                              const float* __restrict__ att2s_g,
                                              const float* __restrict__ att2d_g,
                                              float* __restrict__ h2,
                                              float* __restrict__ a_src2,
                                              float* __restrict__ a_dst2, int N) {
    __shared__ int   sidx[4][CAP];
    __shared__ float sval[4][CAP * 4];
    __shared__ float sout[4][64];
    __shared__ float ws2[64 * 17];   // W2 padded stride 17
    __shared__ float att2s[16], att2d[16];
    int tid = threadIdx.x;
    for (int i = tid; i < 64 * 16; i += 256) {
        int k = i >> 4, c = i & 15;
        ws2[k * 17 + c] = W2[i];
    }
    if (tid < 16) { att2s[tid] = att2s_g[tid]; att2d[tid] = att2d_g[tid]; }
    __syncthreads();   // all threads, before any epilogue read

    int wave = tid >> 6, lane = tid & 63;
    int node = blockIdx.x * 4 + wave;
    bool active = node < N;
    int row = 0, deg = 0;
    float4 ad = make_float4(0.f, 0.f, 0.f, 0.f);
    if (active) {
        row = row_start[node];
        deg = row_start[node + 1] - row;
        ad = ((const float4*)a_dst)[node];
    }
    // phase 1: exp + sum (no-max: logits bounded)
    float s0 = 0.f, s1 = 0.f, s2 = 0.f, s3 = 0.f;
    for (int j = lane; j < deg; j += 64) {
        int s = csr_src[row + j];
        float4 as = ((const float4*)a_src)[s];
        float e0 = __expf(LRELU(as.x + ad.x));
        float e1 = __expf(LRELU(as.y + ad.y));
        float e2 = __expf(LRELU(as.z + ad.z));
        float e3 = __expf(LRELU(as.w + ad.w));
        if (j < CAP) {
            sidx[wave][j] = s;
            *(float4*)&sval[wave][j * 4] = make_float4(e0, e1, e2, e3);
        }
        s0 += e0; s1 += e1; s2 += e2; s3 += e3;
    }
    #pragma unroll
    for (int m = 1; m < 64; m <<= 1) {
        s0 += __shfl_xor(s0, m, 64);
        s1 += __shfl_xor(s1, m, 64);
        s2 += __shfl_xor(s2, m, 64);
        s3 += __shfl_xor(s3, m, 64);
    }
    if (active) {
        // phase 2: 2-edge-parallel gather. lane = cpair(0..31) x epar(0..1)
        int cpair = lane & 31, epar = lane >> 5;
        int head = cpair >> 3;                      // channel 2*cpair -> head
        float ssv = head == 0 ? s0 : head == 1 ? s1 : head == 2 ? s2 : s3;
        float adh = head == 0 ? ad.x : head == 1 ? ad.y : head == 2 ? ad.z : ad.w;
        float iv = 1.f / (ssv + 1e-16f);
        float ax = 0.f, ay = 0.f, bx = 0.f, by = 0.f;
        int dc = deg < CAP ? deg : CAP;
        int j = epar;
        for (; j + 6 < dc; j += 8) {
            int t0 = sidx[wave][j + 0], t1 = sidx[wave][j + 2];
            int t2 = sidx[wave][j + 4], t3 = sidx[wave][j + 6];
            float e0 = sval[wave][(j + 0) * 4 + head], e1 = sval[wave][(j + 2) * 4 + head];
            float e2 = sval[wave][(j + 4) * 4 + head], e3 = sval[wave][(j + 6) * 4 + head];
            float2 g0 = __half22float2(*(const __half2*)&h1[(size_t)t0 * 64 + cpair * 2]);
            float2 g1 = __half22float2(*(const __half2*)&h1[(size_t)t1 * 64 + cpair * 2]);
            float2 g2 = __half22float2(*(const __half2*)&h1[(size_t)t2 * 64 + cpair * 2]);
            float2 g3 = __half22float2(*(const __half2*)&h1[(size_t)t3 * 64 + cpair * 2]);
            ax += e0 * g0.x + e2 * g2.x; ay += e0 * g0.y + e2 * g2.y;
            bx += e1 * g1.x + e3 * g3.x; by += e1 * g1.y + e3 * g3.y;
        }
        for (; j < dc; j += 2) {
            int t = sidx[wave][j];
            float e = sval[wave][j * 4 + head];
            float2 g = __half22float2(*(const __half2*)&h1[(size_t)t * 64 + cpair * 2]);
            ax += e * g.x; ay += e * g.y;
        }
        for (; j < deg; j += 2) {   // deg > CAP fallback
            int s = csr_src[row + j];
            float e = __expf(LRELU(a_src[s * 4 + head] + adh));
            float2 g = __half22float2(*(const __half2*)&h1[(size_t)s * 64 + cpair * 2]);
            ax += e * g.x; ay += e * g.y;
        }
        ax += bx; ay += by;
        ax += __shfl_xor(ax, 32, 64);
        ay += __shfl_xor(ay, 32, 64);
        float2 bb = ((const float2*)bias)[cpair];
        float ox = ax * iv + bb.x;
        float oy = ay * iv + bb.y;
        ox = (ox > 0.f) ? ox : (__expf(ox) - 1.f);   // ELU
        oy = (oy > 0.f) ? oy : (__expf(oy) - 1.f);
        if (epar == 0) {
            sout[wave][cpair * 2 + 0] = ox;
            sout[wave][cpair * 2 + 1] = oy;
        }
        // fused gemm2: h2[c2] = sum_k out1[k]*W2[k][c2] (wave-coherent LDS)
        int c2 = lane & 15, kc = lane >> 4;
        float dot = 0.f;
        #pragma unroll
        for (int i = 0; i < 16; i++)
            dot += sout[wave][kc * 16 + i] * ws2[(kc * 16 + i) * 17 + c2];
        dot += __shfl_xor(dot, 16, 64);
        dot += __shfl_xor(dot, 32, 64);
        if (kc == 0) h2[(size_t)node * 16 + c2] = dot;
        float asv = dot * att2s[c2], adv = dot * att2d[c2];
        #pragma unroll
        for (int m = 1; m < 16; m <<= 1) {
            asv += __shfl_xor(asv, m, 64);
            adv += __shfl_xor(adv, m, 64);
        }
        if (lane == 0) { a_src2[node] = asv; a_dst2[node] = adv; }
    }
}

// layer-2 aggregation + bias + log_softmax; 8-edge-parallel float2 gathers
__global__ __launch_bounds__(256) void k_agg2(const int* __restrict__ row_start,
                                              const int* __restrict__ csr_src,
                                              const float* __restrict__ a_src,
                                              const float* __restrict__ a_dst,
                                              const float* __restrict__ h2,
                                              const float* __restrict__ bias,
                                              float* __restrict__ out, int N) {
    __shared__ int   sidx[4][CAP];
    __shared__ float sval[4][CAP];
    int wave = threadIdx.x >> 6, lane = threadIdx.x & 63;
    int node = blockIdx.x * 4 + wave;
    if (node >= N) return;
    int row = row_start[node];
    int deg = row_start[node + 1] - row;
    float ad = a_dst[node];
    float sh = 0.f;
    for (int j = lane; j < deg; j += 64) {
        int s = csr_src[row + j];
        float e = __expf(LRELU(a_src[s] + ad));
        if (j < CAP) { sidx[wave][j] = s; sval[wave][j] = e; }
        sh += e;
    }
    #pragma unroll
    for (int m = 1; m < 64; m <<= 1) sh += __shfl_xor(sh, m, 64);
    float iv = 1.f / (sh + 1e-16f);
    // gather: lane = cg(0..7 channel pair) x eg(0..7 edge slot)
    int cg = lane & 7, eg = lane >> 3;
    float ax = 0.f, ay = 0.f, bx = 0.f, by = 0.f;
    int dc = deg < CAP ? deg : CAP;
    int j = eg;
    for (; j + 8 < dc; j += 16) {
        int t0 = sidx[wave][j], t1 = sidx[wave][j + 8];
        float e0 = sval[wave][j], e1 = sval[wave][j + 8];
        float2 g0 = ((const float2*)h2)[(size_t)t0 * 8 + cg];
        float2 g1 = ((const float2*)h2)[(size_t)t1 * 8 + cg];
        ax += e0 * g0.x; ay += e0 * g0.y;
        bx += e1 * g1.x; by += e1 * g1.y;
    }
    for (; j < dc; j += 8) {
        int t = sidx[wave][j];
        float e = sval[wave][j];
        float2 g = ((const float2*)h2)[(size_t)t * 8 + cg];
        ax += e * g.x; ay += e * g.y;
    }
    for (; j < deg; j += 8) {   // deg > CAP fallback
        int s = csr_src[row + j];
        float e = __expf(LRELU(a_src[s] + ad));
        float2 g = ((const float2*)h2)[(size_t)s * 8 + cg];
        ax += e * g.x; ay += e * g.y;
    }
    ax += bx; ay += by;
    #pragma unroll
    for (int m = 8; m < 64; m <<= 1) {
        ax += __shfl_xor(ax, m, 64);
        ay += __shfl_xor(ay, m, 64);
    }
    float2 bb = ((const float2*)bias)[cg];
    float vx = ax * iv + bb.x;
    float vy = ay * iv + bb.y;
    // log_softmax over 16 channels (pairs across lanes 0..7 of each eg group)
    float mx = fmaxf(vx, vy);
    #pragma unroll
    for (int m = 1; m < 8; m <<= 1) mx = fmaxf(mx, __shfl_xor(mx, m, 64));
    float se = __expf(vx - mx) + __expf(vy - mx);
    #pragma unroll
    for (int m = 1; m < 8; m <<= 1) se += __shfl_xor(se, m, 64);
    float ls = mx + __logf(se);
    if (eg == 0)
        ((float2*)out)[(size_t)node * 8 + cg] = make_float2(vx - ls, vy - ls);
}

extern "C" void kernel_launch(void* const* d_in, const int* in_sizes, int n_in,
                              void* d_out, int out_size, void* d_ws, size_t ws_size,
                              hipStream_t stream) {
    const float* x        = (const float*)d_in[0];
    const int*   ei       = (const int*)d_in[1];
    const float* W1       = (const float*)d_in[2];
    const float* att_src1 = (const float*)d_in[3];
    const float* att_dst1 = (const float*)d_in[4];
    const float* bias1    = (const float*)d_in[5];
    const float* W2       = (const float*)d_in[6];
    const float* att_src2 = (const float*)d_in[7];
    const float* att_dst2 = (const float*)d_in[8];
    const float* bias2    = (const float*)d_in[9];
    float* out = (float*)d_out;

    const int N = in_sizes[0] / 128;
    const int E = in_sizes[1] / 2;
    const int NBK = (N + 255) >> BSH;

    char* p = (char*)d_ws;
    auto alloc = [&](size_t bytes) -> void* {
        void* r = (void*)p;
        p += (bytes + 255) & ~(size_t)255;
        return r;
    };
    __half* h1     = (__half*)alloc((size_t)N * 64 * 2);
    float* h2      = (float*)alloc((size_t)N * 16 * 4);
    float* a_src1  = (float*)alloc((size_t)N * 4 * 4);
    float* a_dst1  = (float*)alloc((size_t)N * 4 * 4);
    float* a_src2  = (float*)alloc((size_t)N * 4);
    float* a_dst2  = (float*)alloc((size_t)N * 4);
    int*   row_st  = (int*)alloc((size_t)(N + 1) * 4);
    int*   csr     = (int*)alloc((size_t)(E + N) * 4);
    int*   stage   = (int*)alloc((size_t)NBK * BCAP * 4);
    int*   cursor  = (int*)alloc((size_t)NBK * 4);
    int*   gbase   = (int*)alloc((size_t)(NBK + 1) * 4);
    (void)ws_size; (void)n_in; (void)out_size;

    hipMemsetAsync(cursor, 0, (size_t)NBK * 4, stream);
    k_scatter<<<(E + CHK - 1) / CHK, 256, 0, stream>>>(ei, cursor, stage, E, NBK);
    k_bucket_scan<<<1, 256, 0, stream>>>(cursor, gbase, row_st, NBK, E, N);
    k_build<<<NBK, 256, 0, stream>>>(stage, gbase, row_st, csr, N);
    k_gemm1<<<(N + 63) / 64, 256, 0, stream>>>(x, W1, att_src1, att_dst1, h1, a_src1, a_dst1, N);
    k_agg1<<<(N + 3) / 4, 256, 0, stream>>>(row_st, csr, a_src1, a_dst1, h1, bias1,
                                            W2, att_src2, att_dst2, h2, a_src2, a_dst2, N);
    k_agg2<<<(N + 3) / 4, 256, 0, stream>>>(row_st, csr, a_src2, a_dst2, h2, bias2, out, N);
}